// Round 21
// baseline (148.122 us; speedup 1.0000x reference)
//
#include <hip/hip_runtime.h>

typedef unsigned int uint32;
typedef unsigned long long uint64;
typedef unsigned short ushort16;
typedef __attribute__((ext_vector_type(8))) short bf16x8;
typedef __attribute__((ext_vector_type(4))) float f32x4;
typedef __attribute__((ext_vector_type(4))) uint32 u32x4;

#define B_SZ 16384
#define MARGIN 0.012f

// ---------- helpers ----------
__device__ __forceinline__ ushort16 f2bf(float f) {
  uint32 u = __float_as_uint(f);
  u += 0x7fffu + ((u >> 16) & 1u);
  return (ushort16)(u >> 16);
}
__device__ __forceinline__ float bf2f(ushort16 h) { return __uint_as_float(((uint32)h) << 16); }
__device__ __forceinline__ float bflo(uint32 u) { return __uint_as_float(u << 16); }
__device__ __forceinline__ float bfhi(uint32 u) { return __uint_as_float(u & 0xffff0000u); }
__device__ __forceinline__ uint32 pk2(float lo, float hi) {
  return ((uint32)f2bf(hi) << 16) | (uint32)f2bf(lo);
}
__device__ __forceinline__ int dot4(uint32 a, uint32 b, int c) {
#if __has_builtin(__builtin_amdgcn_sdot4)
  return __builtin_amdgcn_sdot4((int)a, (int)b, c, false);
#else
  int s = c;
#pragma unroll
  for (int k = 0; k < 4; ++k)
    s += (int)(char)(a >> (8 * k)) * (int)(char)(b >> (8 * k));
  return s;
#endif
}
__device__ __forceinline__ int q8(float v, float inv) {
  int q = (int)rintf(v * inv);
  return q > 127 ? 127 : (q < -127 ? -127 : q);
}
// 16-lane-row sum via DPP (VALU pipe, no LDS)
__device__ __forceinline__ int red16_i(int s) {
  s += __builtin_amdgcn_update_dpp(0, s, 0xB1, 0xF, 0xF, true);   // quad_perm [1,0,3,2]
  s += __builtin_amdgcn_update_dpp(0, s, 0x4E, 0xF, 0xF, true);   // quad_perm [2,3,0,1]
  s += __builtin_amdgcn_update_dpp(0, s, 0x141, 0xF, 0xF, true);  // row_half_mirror
  s += __builtin_amdgcn_update_dpp(0, s, 0x140, 0xF, 0xF, true);  // row_mirror
  return s;
}
#define DPP_D_LEVEL(v, ctrl)                                                        \
  {                                                                                 \
    uint64 u_ = (uint64)__double_as_longlong(v);                                    \
    int lo_ = __builtin_amdgcn_update_dpp(0, (int)(uint32)u_, (ctrl), 0xF, 0xF, true); \
    int hi_ = __builtin_amdgcn_update_dpp(0, (int)(uint32)(u_ >> 32), (ctrl), 0xF, 0xF, true); \
    (v) += __longlong_as_double((long long)(((uint64)(uint32)hi_ << 32) | (uint32)lo_)); \
  }
__device__ __forceinline__ double red16_d(double v) {
  DPP_D_LEVEL(v, 0xB1); DPP_D_LEVEL(v, 0x4E);
  DPP_D_LEVEL(v, 0x141); DPP_D_LEVEL(v, 0x140);
  return v;
}

// ---------- prep: [0,3584) Wall(896 rows) | [3584,11776) x -> xb bf16 pack ----------
__global__ __launch_bounds__(256) void prep_all(
    const float* __restrict__ Wfc, const float* __restrict__ Wbin,
    const float* __restrict__ x, ushort16* __restrict__ Wall,
    u32x4* __restrict__ xb) {
  const int blk = blockIdx.x;
  const int t = threadIdx.x;
  if (blk < 3584) {
    int idx = blk * 256 + t;                     // 896*1024
    int j = idx >> 10, n = idx & 1023;
    float v = 0.f;
    if (j < 12) v = Wfc[n * 12 + j];
    else if (j >= 64 && j < 832) v = Wbin[(size_t)(j - 64) * 1024 + n];
    Wall[idx] = f2bf(v);
  } else {
    int idx = (blk - 3584) * 256 + t;            // 2,097,152 threads x 8 floats
    const float4* s = (const float4*)x + (size_t)idx * 2;
    float4 a = s[0], b4 = s[1];
    u32x4 o;
    o.x = pk2(a.x, a.y);  o.y = pk2(a.z, a.w);
    o.z = pk2(b4.x, b4.y); o.w = pk2(b4.z, b4.w);
    xb[idx] = o;
  }
}

// ---------- legacy preps for fallback ----------
__global__ void prep_wall_f(const float* __restrict__ Wfc, const float* __restrict__ Wbin,
                            ushort16* __restrict__ Wall) {
  int idx = blockIdx.x * 256 + threadIdx.x;      // 896*1024
  int j = idx >> 10, n = idx & 1023;
  float v = 0.f;
  if (j < 12) v = Wfc[n * 12 + j];
  else if (j >= 64 && j < 832) v = Wbin[(size_t)(j - 64) * 1024 + n];
  Wall[idx] = f2bf(v);
}
__global__ void prep_wres(const float* __restrict__ Wres, ushort16* __restrict__ Wres_b) {
  int idx = blockIdx.x * 256 + threadIdx.x;
  int n = idx & 1023;
  int d = (idx >> 10) % 3;
  int ck = idx / 3072;
  Wres_b[idx] = f2bf(Wres[((size_t)ck * 1024 + n) * 3 + d]);
}

// ---------- legacy 128x128 gemm for fallback (256 thr, writes ybin) ----------
__global__ __launch_bounds__(256) void gemm_fb(
    const float* __restrict__ x, const float* __restrict__ bfc,
    const float* __restrict__ bbin, const ushort16* __restrict__ Wall,
    ushort16* __restrict__ ybin, float* __restrict__ out) {
  __shared__ __align__(16) char smem[32768];
  const int t = threadIdx.x;
  const int lane = t & 63, wid = t >> 6;
  const int wm = wid & 1, wn = wid >> 1;
  int orig = blockIdx.x;
  int bid = (orig & 7) * 112 + (orig >> 3);
  int nb = bid % 7, mb = bid / 7;
  const int b0 = mb * 128;
  f32x4 acc[4][4];
#pragma unroll
  for (int i = 0; i < 4; ++i)
#pragma unroll
    for (int j = 0; j < 4; ++j) acc[i][j] = (f32x4){0.f, 0.f, 0.f, 0.f};
  const int lr = lane & 15, lq = lane >> 4;
  const int fxor = (lr & 7) << 4;
  for (int kc = 0; kc < 1024; kc += 64) {
    __syncthreads();
    const int sxor = ((t >> 3) & 7) << 4;
#pragma unroll
    for (int i = 0; i < 4; ++i) {
      int s = t + i * 256;
      int row = s >> 3, c8 = (s & 7) * 8;
      int dst = row * 128 + ((c8 * 2) ^ sxor);
      const float4* src = (const float4*)(x + (size_t)(b0 + row) * 1024 + kc + c8);
      float4 v0 = src[0], v1 = src[1];
      u32x4 pv;
      pv.x = pk2(v0.x, v0.y); pv.y = pk2(v0.z, v0.w);
      pv.z = pk2(v1.x, v1.y); pv.w = pk2(v1.z, v1.w);
      *(u32x4*)(smem + dst) = pv;
    }
#pragma unroll
    for (int i = 0; i < 4; ++i) {
      int s = t + i * 256;
      int row = s >> 3, c8 = (s & 7) * 8;
      int dst = 16384 + row * 128 + ((c8 * 2) ^ sxor);
      u32x4 v = *(const u32x4*)(Wall + (size_t)(nb * 128 + row) * 1024 + kc + c8);
      *(u32x4*)(smem + dst) = v;
    }
    __syncthreads();
#pragma unroll
    for (int kk = 0; kk < 2; ++kk) {
      int cbx = (kk * 64 + lq * 16) ^ fxor;
      bf16x8 af[4], bfr[4];
#pragma unroll
      for (int i = 0; i < 4; ++i)
        af[i] = *(const bf16x8*)(smem + (wm * 64 + i * 16 + lr) * 128 + cbx);
#pragma unroll
      for (int j = 0; j < 4; ++j)
        bfr[j] = *(const bf16x8*)(smem + 16384 + (wn * 64 + j * 16 + lr) * 128 + cbx);
#pragma unroll
      for (int i = 0; i < 4; ++i)
#pragma unroll
        for (int j = 0; j < 4; ++j)
          acc[i][j] = __builtin_amdgcn_mfma_f32_16x16x32_bf16(af[i], bfr[j], acc[i][j], 0, 0, 0);
    }
  }
  const int g = 2 * nb + wn;
  if (g == 0) {
#pragma unroll
    for (int i = 0; i < 4; ++i)
#pragma unroll
      for (int r = 0; r < 4; ++r) {
        int gm = b0 + wm * 64 + i * 16 + lq * 4 + r;
        if (lr < 12) out[(size_t)gm * 12 + lr] = acc[i][0][r] + bfc[lr];
      }
    return;
  }
  if (g > 12) return;
  const int c = g - 1;
#pragma unroll
  for (int i = 0; i < 4; ++i)
#pragma unroll
    for (int j = 0; j < 4; ++j)
#pragma unroll
      for (int r = 0; r < 4; ++r) {
        int gm = b0 + wm * 64 + i * 16 + lq * 4 + r;
        int col = j * 16 + lr;
        ybin[((size_t)gm * 12 + c) * 64 + col] = f2bf(acc[i][j][r] + bbin[c * 64 + col]);
      }
}

// ---------- mega-kernel, 512 thr: [0,448) GEMM 256x128 | [448,544) Wres quant | [544,2592) xq ----------
__global__ __launch_bounds__(512) void gemm_mega(
    const float* __restrict__ x, const ushort16* __restrict__ xb,
    const float* __restrict__ bfc, const float* __restrict__ bbin,
    const ushort16* __restrict__ Wall, unsigned char* __restrict__ ind8,
    uint64* __restrict__ mask64, const float* __restrict__ Wres,
    uint32* __restrict__ wq, float* __restrict__ swk, uint32* __restrict__ xq,
    float* __restrict__ sxb, float* __restrict__ out) {
  extern __shared__ __align__(16) char smem[];   // 73728 B for gemm blocks
  const int t = threadIdx.x;
  const int lane = t & 63, wid = t >> 6;

  if (blockIdx.x >= 544) {
    // ---- xq + sxb prep, wave-per-row ----
    const int b = (blockIdx.x - 544) * 8 + wid;  // 2048 blocks x 8 waves
    const float4* xr = (const float4*)(x + (size_t)b * 1024 + lane * 16);
    float4 v0 = xr[0], v1 = xr[1], v2 = xr[2], v3 = xr[3];
    float xv[16] = {v0.x, v0.y, v0.z, v0.w, v1.x, v1.y, v1.z, v1.w,
                    v2.x, v2.y, v2.z, v2.w, v3.x, v3.y, v3.z, v3.w};
    float m = 0.f;
#pragma unroll
    for (int i = 0; i < 16; ++i) m = fmaxf(m, fabsf(xv[i]));
    for (int off = 32; off; off >>= 1) m = fmaxf(m, __shfl_xor(m, off));
    float mx = fmaxf(m, 1e-20f);
    float inv = 127.f / mx;
    if (lane == 0) sxb[b] = mx / 127.f;
    u32x4 qv;
#pragma unroll
    for (int q = 0; q < 4; ++q) {
      uint32 u = ((uint32)(unsigned char)(char)q8(xv[4 * q + 0], inv)) |
                 ((uint32)(unsigned char)(char)q8(xv[4 * q + 1], inv)) << 8 |
                 ((uint32)(unsigned char)(char)q8(xv[4 * q + 2], inv)) << 16 |
                 ((uint32)(unsigned char)(char)q8(xv[4 * q + 3], inv)) << 24;
      qv[q] = u;
    }
    ((u32x4*)(xq + (size_t)b * 256))[lane] = qv;
    return;
  }
  if (blockIdx.x >= 448) {
    // ---- Wres -> int8 quant, wave-per-ck ----
    const int ck = (blockIdx.x - 448) * 8 + wid; // 96 blocks x 8 waves = 768 experts
    const float4* base4 = (const float4*)(Wres + (size_t)ck * 3072);
    float m = 0.f;
#pragma unroll
    for (int it = 0; it < 4; ++it) {
      int tt = lane + 64 * it;
      float4 v0 = base4[3 * tt], v1 = base4[3 * tt + 1], v2 = base4[3 * tt + 2];
      m = fmaxf(m, fmaxf(fmaxf(fabsf(v0.x), fabsf(v0.y)), fmaxf(fabsf(v0.z), fabsf(v0.w))));
      m = fmaxf(m, fmaxf(fmaxf(fabsf(v1.x), fabsf(v1.y)), fmaxf(fabsf(v1.z), fabsf(v1.w))));
      m = fmaxf(m, fmaxf(fmaxf(fabsf(v2.x), fabsf(v2.y)), fmaxf(fabsf(v2.z), fabsf(v2.w))));
    }
    for (int off = 32; off; off >>= 1) m = fmaxf(m, __shfl_xor(m, off));
    float mx = fmaxf(m, 1e-20f);
    float inv = 127.f / mx;
    if (lane == 0) swk[ck] = mx / 127.f;
#pragma unroll
    for (int it = 0; it < 4; ++it) {
      int tt = lane + 64 * it;
      float4 v0 = base4[3 * tt], v1 = base4[3 * tt + 1], v2 = base4[3 * tt + 2];
      float vals[12] = {v0.x, v0.y, v0.z, v0.w, v1.x, v1.y, v1.z, v1.w, v2.x, v2.y, v2.z, v2.w};
#pragma unroll
      for (int d = 0; d < 3; ++d) {
        uint32 u = 0;
#pragma unroll
        for (int j = 0; j < 4; ++j)
          u |= ((uint32)(unsigned char)(char)q8(vals[j * 3 + d], inv)) << (8 * j);
        wq[((size_t)(ck * 3 + d) << 8) + tt] = u;
      }
    }
    return;
  }

  // ---- GEMM path: BM=256 BN=128 BK=32, 8 waves (4M x 2N) ----
  const int wm = wid & 3, wn = wid >> 2;

  int orig = blockIdx.x;
  int bid = (orig & 7) * 56 + (orig >> 3);       // XCD-bijective (448 = 8*56)
  int nb = bid % 7, mb = bid / 7;
  const int b0 = mb * 256;

  f32x4 acc[4][4];
#pragma unroll
  for (int i = 0; i < 4; ++i)
#pragma unroll
    for (int j = 0; j < 4; ++j) acc[i][j] = (f32x4){0.f, 0.f, 0.f, 0.f};

  const int lr = lane & 15, lq = lane >> 4;
  const int gs2 = (lane & 3) ^ ((lane >> 2) & 3);
  const int grw2 = lane >> 2;

#define GLDS(srcp, dstoff)                                                      \
  __builtin_amdgcn_global_load_lds(                                             \
      (const __attribute__((address_space(1))) uint32*)(srcp),                  \
      (__attribute__((address_space(3))) uint32*)(smem + (dstoff)), 16, 0, 0)

  const ushort16* srcp[3];
  int dsto[3];
#pragma unroll
  for (int k = 0; k < 3; ++k) {
    int c = wid * 3 + k;
    if (c < 16) {
      srcp[k] = xb + (size_t)(b0 + c * 16 + grw2) * 1024 + gs2 * 8;
      dsto[k] = c * 1024;
    } else {
      int cb = c - 16;
      srcp[k] = Wall + (size_t)(nb * 128 + cb * 16 + grw2) * 1024 + gs2 * 8;
      dsto[k] = 16384 + cb * 1024;
    }
  }

#define STAGE_HALF(h, buf)                                                      \
  {                                                                             \
    int bb_ = (buf) * 24576;                                                    \
    int kc_ = (h) * 32;                                                         \
    GLDS(srcp[0] + kc_, bb_ + dsto[0]);                                         \
    GLDS(srcp[1] + kc_, bb_ + dsto[1]);                                         \
    GLDS(srcp[2] + kc_, bb_ + dsto[2]);                                         \
  }

  STAGE_HALF(0, 0); STAGE_HALF(1, 1);
  const int cbx2 = (lq * 16) ^ ((lr & 3) << 4);
  const int arow_off = (wm * 64 + lr) * 64;
  const int brow_off = (wn * 64 + lr) * 64;
  int rb = 0;
#pragma unroll 1
  for (int h = 0; h < 32; ++h) {
    if (h < 31) asm volatile("s_waitcnt vmcnt(3)" ::: "memory");
    else        asm volatile("s_waitcnt vmcnt(0)" ::: "memory");
    __builtin_amdgcn_s_barrier();
    if (h < 30) {
      int sb = rb + 2; if (sb >= 3) sb -= 3;
      STAGE_HALF(h + 2, sb);
    }
    const char* base = smem + rb * 24576;
    bf16x8 af[4], bfr[4];
#pragma unroll
    for (int i = 0; i < 4; ++i)
      af[i] = *(const bf16x8*)(base + arow_off + i * 1024 + cbx2);
#pragma unroll
    for (int j = 0; j < 4; ++j)
      bfr[j] = *(const bf16x8*)(base + 16384 + brow_off + j * 1024 + cbx2);
#pragma unroll
    for (int i = 0; i < 4; ++i)
#pragma unroll
      for (int j = 0; j < 4; ++j)
        acc[i][j] = __builtin_amdgcn_mfma_f32_16x16x32_bf16(af[i], bfr[j], acc[i][j], 0, 0, 0);
    rb = (rb == 2) ? 0 : rb + 1;
  }
#undef STAGE_HALF
#undef GLDS

  // ---- epilogue ----
  const int g = 2 * nb + wn;                     // group id 0..13
  if (g == 0) {
#pragma unroll
    for (int i = 0; i < 4; ++i)
#pragma unroll
      for (int r = 0; r < 4; ++r) {
        int gm = b0 + wm * 64 + i * 16 + lq * 4 + r;
        if (lr < 12) out[(size_t)gm * 12 + lr] = acc[i][0][r] + bfc[lr];
      }
    return;
  }
  if (g > 12) return;
  const int c = g - 1;
  float bb[4];
#pragma unroll
  for (int j = 0; j < 4; ++j) bb[j] = bbin[c * 64 + j * 16 + lr];
#pragma unroll
  for (int i = 0; i < 4; ++i)
#pragma unroll
    for (int r = 0; r < 4; ++r) {
      float v0 = acc[i][0][r] + bb[0], v1 = acc[i][1][r] + bb[1];
      float v2 = acc[i][2][r] + bb[2], v3 = acc[i][3][r] + bb[3];
      float m1 = v0, m2 = -3.4e38f; int k1 = lr;
      if (v1 > m1) { m2 = m1; m1 = v1; k1 = 16 + lr; } else m2 = fmaxf(m2, v1);
      if (v2 > m1) { m2 = m1; m1 = v2; k1 = 32 + lr; } else m2 = fmaxf(m2, v2);
      if (v3 > m1) { m2 = m1; m1 = v3; k1 = 48 + lr; } else m2 = fmaxf(m2, v3);
#pragma unroll
      for (int off = 1; off < 16; off <<= 1) {
        float om1 = __shfl_xor(m1, off);
        int   ok1 = __shfl_xor(k1, off);
        float om2 = __shfl_xor(m2, off);
        bool take = (om1 > m1) || (om1 == m1 && ok1 < k1);
        float lose = take ? m1 : om1;
        m2 = fmaxf(fmaxf(m2, om2), lose);
        if (take) { m1 = om1; k1 = ok1; }
      }
      float thr = m1 - MARGIN;
      uint64 bl0 = __ballot(v0 >= thr);
      uint64 bl1 = __ballot(v1 >= thr);
      uint64 bl2 = __ballot(v2 >= thr);
      uint64 bl3 = __ballot(v3 >= thr);
      if (lr == 0) {
        int row = wm * 64 + i * 16 + lq * 4 + r;
        uint64 mk = ((bl0 >> (lq * 16)) & 0xffffull) |
                    (((bl1 >> (lq * 16)) & 0xffffull) << 16) |
                    (((bl2 >> (lq * 16)) & 0xffffull) << 32) |
                    (((bl3 >> (lq * 16)) & 0xffffull) << 48);
        int gp = (b0 + row) * 12 + c;
        ind8[gp] = (unsigned char)(k1 | ((m1 - m2 <= MARGIN) ? 128 : 0));
        mask64[gp] = mk;
      }
    }
}

// ---------- compact_k ----------
__global__ __launch_bounds__(256) void compact_k(const unsigned char* __restrict__ ind8,
                                                 uint32* __restrict__ cnt,
                                                 uint32* __restrict__ wl) {
  const int b = blockIdx.x * 256 + threadIdx.x;  // 64 blocks
  const int lane = threadIdx.x & 63;
  const uint32* p = (const uint32*)(ind8 + b * 12);
  uint32 d0 = p[0], d1 = p[1], d2 = p[2];
  uint32 fmask = 0;
#pragma unroll
  for (int j = 0; j < 4; ++j) {
    if ((d0 >> (8 * j)) & 128u) fmask |= 1u << j;
    if ((d1 >> (8 * j)) & 128u) fmask |= 1u << (4 + j);
    if ((d2 >> (8 * j)) & 128u) fmask |= 1u << (8 + j);
  }
  uint32 n_i = (uint32)__popc(fmask);
  uint32 pre = n_i;
  for (int off = 1; off < 64; off <<= 1) {
    uint32 v = __shfl_up(pre, off);
    if (lane >= off) pre += v;
  }
  uint32 total = __shfl(pre, 63);
  uint32 base = 0;
  if (lane == 63 && total) base = atomicAdd(cnt, total);
  base = __shfl(base, 63);
  uint32 off = base + pre - n_i;
  while (fmask) {
    int c = __ffs(fmask) - 1;
    fmask &= fmask - 1;
    wl[off++] = (uint32)(b * 12 + c);
  }
}

// ---------- tail_k (grid 8192): bid&1==0 -> rescue (16384 slots); ==1 -> gather 1-wave-per-b ----------
__global__ __launch_bounds__(256) void tail_k(
    const float* __restrict__ x, const float* __restrict__ Wbin,
    const float* __restrict__ bbin, const float* __restrict__ bres,
    const float* __restrict__ centers, const unsigned char* __restrict__ ind8,
    const uint64* __restrict__ mask64, const uint32* __restrict__ wq,
    const float* __restrict__ swk, const uint32* __restrict__ xq,
    const float* __restrict__ sxb, const uint32* __restrict__ cnt,
    const uint32* __restrict__ wl, float* __restrict__ out) {
  const int lane = threadIdx.x & 63;
  const int w = threadIdx.x >> 6;
  const int rm = (int)(blockIdx.x & 1u);
  const int rq = (int)(blockIdx.x >> 1);

  if (rm == 0) {
    // ---- per-pair rescue; 4096 blocks -> 16384 wave slots, grid-stride ----
    const uint32 nresc = *cnt;
#pragma unroll 1
    for (uint32 slot = (uint32)rq * 4 + w; slot < nresc; slot += 16384) {
      const uint32 pp = wl[slot];
      const int b = (int)(pp / 12u), c = (int)(pp % 12u);

      float xv[16];
      const float4* xr = (const float4*)(x + (size_t)b * 1024 + lane * 16);
#pragma unroll
      for (int q = 0; q < 4; ++q) {
        float4 vv = xr[q];
        xv[4 * q] = vv.x; xv[4 * q + 1] = vv.y; xv[4 * q + 2] = vv.z; xv[4 * q + 3] = vv.w;
      }
      const float sx = sxb[b];
      const u32x4 xi = *(const u32x4*)(xq + (size_t)b * 256 + lane * 4);  // stored bytes (bit-identical)

      uint64 mask = mask64[pp];
      double best = -1.0e300;
      int bk = 0;
#pragma unroll 1
      while (mask) {
        int kk[4];
        int nc = 0;
        while (mask && nc < 4) { kk[nc++] = __ffsll(mask) - 1; mask &= mask - 1; }
#pragma unroll
        for (int j = 1; j < 4; ++j) if (j >= nc) kk[j] = kk[0];
        double s[4] = {0.0, 0.0, 0.0, 0.0};
#pragma unroll
        for (int ci = 0; ci < 4; ++ci) {
          const float4* wr4 = (const float4*)(Wbin + ((size_t)c * 64 + kk[ci]) * 1024 + lane * 16);
#pragma unroll
          for (int q = 0; q < 4; ++q) {
            float4 wvv = wr4[q];
            s[ci] += (double)xv[4 * q] * (double)wvv.x + (double)xv[4 * q + 1] * (double)wvv.y +
                     (double)xv[4 * q + 2] * (double)wvv.z + (double)xv[4 * q + 3] * (double)wvv.w;
          }
        }
#pragma unroll
        for (int ci = 0; ci < 4; ++ci) s[ci] = red16_d(s[ci]);   // DPP 16-lane sums
        for (int off = 16; off < 64; off <<= 1) {
#pragma unroll
          for (int ci = 0; ci < 4; ++ci) s[ci] += __shfl_xor(s[ci], off);
        }
#pragma unroll
        for (int ci = 0; ci < 4; ++ci) {
          double sv = s[ci] + (double)bbin[c * 64 + kk[ci]];
          if (ci < nc && sv > best) { best = sv; bk = kk[ci]; }  // ascending k, strict >
        }
      }
      const int ck = c * 64 + bk;
      const uint32* wr = wq + (size_t)ck * 768;
      int acc[3];
#pragma unroll
      for (int d = 0; d < 3; ++d) {
        u32x4 wvq = *(const u32x4*)(wr + d * 256 + lane * 4);
        int ss = dot4(xi.x, wvq.x, 0);
        ss = dot4(xi.y, wvq.y, ss);
        ss = dot4(xi.z, wvq.z, ss);
        acc[d] = dot4(xi.w, wvq.w, ss);
      }
#pragma unroll
      for (int d = 0; d < 3; ++d) acc[d] = red16_i(acc[d]);
      for (int off = 16; off < 64; off <<= 1) {
        acc[0] += __shfl_xor(acc[0], off);
        acc[1] += __shfl_xor(acc[1], off);
        acc[2] += __shfl_xor(acc[2], off);
      }
      if (lane == 0) {
        const size_t obase = (size_t)B_SZ * 12 + (size_t)b * 36;
        float sc = sx * swk[ck];
        out[obase + 0 * 12 + c] = centers[bk * 3 + 0] + bres[ck * 3 + 0] + sc * (float)acc[0];
        out[obase + 1 * 12 + c] = centers[bk * 3 + 1] + bres[ck * 3 + 1] + sc * (float)acc[1];
        out[obase + 2 * 12 + c] = centers[bk * 3 + 2] + bres[ck * 3 + 2] + sc * (float)acc[2];
      }
    }
    return;
  }

  // ---- gather: 1 wave per b (4 b's per block); 12 classes in 4 groups of 3 ----
  const int b = rq * 4 + w;                      // 4096 gather blocks -> 16384 b's

  const u32x4 xi = *(const u32x4*)(xq + (size_t)b * 256 + lane * 4);
  const float sx = sxb[b];
  const size_t obase = (size_t)B_SZ * 12 + (size_t)b * 36;

  const uint32* pv = (const uint32*)(ind8 + b * 12);
  uint32 ivd[3] = {pv[0], pv[1], pv[2]};

#pragma unroll
  for (int cg = 0; cg < 4; ++cg) {
#pragma unroll
    for (int cc = 0; cc < 3; ++cc) {
      int c = cg * 3 + cc;
      int iv = (int)((ivd[c >> 2] >> ((c & 3) * 8)) & 255u);
      if (iv & 128) continue;                    // flagged handled by rescue (wave-uniform skip)
      int ind = iv & 63;
      int ck = c * 64 + ind;
      const uint32* wr = wq + (size_t)ck * 768;
      u32x4 wv0 = *(const u32x4*)(wr + 0 * 256 + lane * 4);
      u32x4 wv1 = *(const u32x4*)(wr + 1 * 256 + lane * 4);
      u32x4 wv2 = *(const u32x4*)(wr + 2 * 256 + lane * 4);
      int a0 = dot4(xi.w, wv0.w, dot4(xi.z, wv0.z, dot4(xi.y, wv0.y, dot4(xi.x, wv0.x, 0))));
      int a1 = dot4(xi.w, wv1.w, dot4(xi.z, wv1.z, dot4(xi.y, wv1.y, dot4(xi.x, wv1.x, 0))));
      int a2 = dot4(xi.w, wv2.w, dot4(xi.z, wv2.z, dot4(xi.y, wv2.y, dot4(xi.x, wv2.x, 0))));
      a0 = red16_i(a0); a1 = red16_i(a1); a2 = red16_i(a2);
      for (int off = 16; off < 64; off <<= 1) {
        a0 += __shfl_xor(a0, off);
        a1 += __shfl_xor(a1, off);
        a2 += __shfl_xor(a2, off);
      }
      if (lane == 0) {
        float sc = sx * swk[ck];
        out[obase + 0 * 12 + c] = centers[ind * 3 + 0] + bres[ck * 3 + 0] + sc * (float)a0;
        out[obase + 1 * 12 + c] = centers[ind * 3 + 1] + bres[ck * 3 + 1] + sc * (float)a1;
        out[obase + 2 * 12 + c] = centers[ind * 3 + 2] + bres[ck * 3 + 2] + sc * (float)a2;
      }
    }
  }
}

// ---------- fallback select (bf16 Wres_b, f32 x, reads ybin) ----------
__global__ __launch_bounds__(256) void select2(
    const float* __restrict__ x, const float* __restrict__ Wbin,
    const float* __restrict__ bbin, const float* __restrict__ bres,
    const float* __restrict__ centers, const ushort16* __restrict__ Wres_b,
    const ushort16* __restrict__ ybin, float* __restrict__ out) {
  const int lane = threadIdx.x & 63;
  const int w = threadIdx.x >> 6;
  const int b = blockIdx.x;
  float xv[16];
  {
    const float4* xr = (const float4*)(x + (size_t)b * 1024 + lane * 16);
#pragma unroll
    for (int q = 0; q < 4; ++q) {
      float4 v = xr[q];
      xv[4 * q] = v.x; xv[4 * q + 1] = v.y; xv[4 * q + 2] = v.z; xv[4 * q + 3] = v.w;
    }
  }
  const size_t obase = (size_t)B_SZ * 12 + (size_t)b * 36;
#pragma unroll 1
  for (int cc = 0; cc < 3; ++cc) {
    const int c = w * 3 + cc;
    float v = bf2f(ybin[((size_t)b * 12 + c) * 64 + lane]);
    float m1 = v, m2 = -3.4e38f;
    int k1 = lane;
    for (int off = 32; off; off >>= 1) {
      float om1 = __shfl_xor(m1, off);
      int   ok1 = __shfl_xor(k1, off);
      float om2 = __shfl_xor(m2, off);
      bool take = (om1 > m1) || (om1 == m1 && ok1 < k1);
      float lose = take ? m1 : om1;
      m2 = fmaxf(fmaxf(m2, om2), lose);
      if (take) { m1 = om1; k1 = ok1; }
    }
    int ind = k1;
    if (m1 - m2 <= MARGIN) {
      unsigned long long mask = __ballot(v >= m1 - MARGIN);
      double best = -1.0e300;
      int bk = 0;
      while (mask) {
        int k = __ffsll(mask) - 1;
        mask &= (mask - 1);
        const float4* wr4 = (const float4*)(Wbin + ((size_t)c * 64 + k) * 1024 + lane * 16);
        double s = 0.0;
#pragma unroll
        for (int q = 0; q < 4; ++q) {
          float4 wv = wr4[q];
          s += (double)xv[4 * q] * (double)wv.x + (double)xv[4 * q + 1] * (double)wv.y +
               (double)xv[4 * q + 2] * (double)wv.z + (double)xv[4 * q + 3] * (double)wv.w;
        }
        for (int off = 32; off; off >>= 1) s += __shfl_xor(s, off);
        s += (double)bbin[c * 64 + k];
        if (s > best) { best = s; bk = k; }
      }
      ind = bk;
    }
    const ushort16* wr = Wres_b + ((size_t)(c * 64 + ind) * 3) * 1024;
    float a[3] = {0.f, 0.f, 0.f};
#pragma unroll
    for (int d = 0; d < 3; ++d) {
      const u32x4* pp = (const u32x4*)(wr + d * 1024 + lane * 16);
      u32x4 w0 = pp[0], w1 = pp[1];
      uint32 uw[8] = {w0.x, w0.y, w0.z, w0.w, w1.x, w1.y, w1.z, w1.w};
#pragma unroll
      for (int q = 0; q < 8; ++q) {
        a[d] = fmaf(xv[2 * q],     bflo(uw[q]), a[d]);
        a[d] = fmaf(xv[2 * q + 1], bfhi(uw[q]), a[d]);
      }
    }
    for (int off = 32; off; off >>= 1) {
      a[0] += __shfl_xor(a[0], off);
      a[1] += __shfl_xor(a[1], off);
      a[2] += __shfl_xor(a[2], off);
    }
    if (lane == 0) {
      int ck = c * 64 + ind;
      out[obase + 0 * 12 + c] = centers[ind * 3 + 0] + bres[ck * 3 + 0] + a[0];
      out[obase + 1 * 12 + c] = centers[ind * 3 + 1] + bres[ck * 3 + 1] + a[1];
      out[obase + 2 * 12 + c] = centers[ind * 3 + 2] + bres[ck * 3 + 2] + a[2];
    }
  }
}

extern "C" void kernel_launch(void* const* d_in, const int* in_sizes, int n_in,
                              void* d_out, int out_size, void* d_ws, size_t ws_size,
                              hipStream_t stream) {
  const float* x       = (const float*)d_in[0];
  const float* Wfc     = (const float*)d_in[1];
  const float* bfc     = (const float*)d_in[2];
  const float* Wbin    = (const float*)d_in[3];
  const float* bbin    = (const float*)d_in[4];
  const float* Wres    = (const float*)d_in[5];
  const float* bres    = (const float*)d_in[6];
  const float* centers = (const float*)d_in[7];
  float* out = (float*)d_out;

  char* ws = (char*)d_ws;
  ushort16* Wall = (ushort16*)ws;                              // 896*1024*2 = 1,835,008 B
  if (ws_size >= 57151488ull) {
    uint32*        wq     = (uint32*)(ws + 1835008);           // 2,359,296 B
    float*         swk    = (float*)(ws + 4194304);            // 3,072 B
    unsigned char* ind8   = (unsigned char*)(ws + 4197376);    // 196,608 B
    uint64*        mask64 = (uint64*)(ws + 4393984);           // 1,572,864 B
    ushort16*      xb     = (ushort16*)(ws + 5966848);         // 33,554,432 B
    uint32*        xq     = (uint32*)(ws + 39521280);          // 16,777,216 B
    float*         sxb    = (float*)(ws + 56298496);           // 65,536 B
    uint32*        cnt    = (uint32*)(ws + 56364032);          // 256 B (pad)
    uint32*        wl     = (uint32*)(ws + 56364288);          // 786,432 B -> end 57,150,720

    (void)hipFuncSetAttribute((const void*)gemm_mega,
                              hipFuncAttributeMaxDynamicSharedMemorySize, 73728);
    hipMemsetAsync(cnt, 0, 4, stream);
    prep_all<<<11776, 256, 0, stream>>>(Wfc, Wbin, x, Wall, (u32x4*)xb);
    gemm_mega<<<2592, 512, 73728, stream>>>(x, xb, bfc, bbin, Wall, ind8, mask64,
                                            Wres, wq, swk, xq, sxb, out);
    compact_k<<<64, 256, 0, stream>>>(ind8, cnt, wl);
    tail_k<<<8192, 256, 0, stream>>>(x, Wbin, bbin, bres, centers, ind8, mask64,
                                     wq, swk, xq, sxb, cnt, wl, out);
  } else {
    // fallback: ybin + bf16 select path
    ushort16* Wres_b = (ushort16*)(ws + 1835008);              // 4,718,592 B
    ushort16* ybin   = (ushort16*)(ws + 6553600);              // 25,165,824 B
    prep_wall_f<<<3584, 256, 0, stream>>>(Wfc, Wbin, Wall);
    prep_wres<<<9216, 256, 0, stream>>>(Wres, Wres_b);
    gemm_fb<<<896, 256, 0, stream>>>(x, bfc, bbin, Wall, ybin, out);
    select2<<<B_SZ, 256, 0, stream>>>(x, Wbin, bbin, bres, centers, Wres_b, ybin, out);
  }
}

// Round 22
// 129.929 us; speedup vs baseline: 1.1400x; 1.1400x over previous
//
#include <hip/hip_runtime.h>

typedef unsigned int uint32;
typedef unsigned long long uint64;
typedef unsigned short ushort16;
typedef __attribute__((ext_vector_type(8))) short bf16x8;
typedef __attribute__((ext_vector_type(4))) float f32x4;
typedef __attribute__((ext_vector_type(4))) uint32 u32x4;

#define B_SZ 16384
#define MARGIN 0.012f

// ---------- helpers ----------
__device__ __forceinline__ ushort16 f2bf(float f) {
  uint32 u = __float_as_uint(f);
  u += 0x7fffu + ((u >> 16) & 1u);
  return (ushort16)(u >> 16);
}
__device__ __forceinline__ float bf2f(ushort16 h) { return __uint_as_float(((uint32)h) << 16); }
__device__ __forceinline__ float bflo(uint32 u) { return __uint_as_float(u << 16); }
__device__ __forceinline__ float bfhi(uint32 u) { return __uint_as_float(u & 0xffff0000u); }
__device__ __forceinline__ uint32 pk2(float lo, float hi) {
  return ((uint32)f2bf(hi) << 16) | (uint32)f2bf(lo);
}
__device__ __forceinline__ int dot4(uint32 a, uint32 b, int c) {
#if __has_builtin(__builtin_amdgcn_sdot4)
  return __builtin_amdgcn_sdot4((int)a, (int)b, c, false);
#else
  int s = c;
#pragma unroll
  for (int k = 0; k < 4; ++k)
    s += (int)(char)(a >> (8 * k)) * (int)(char)(b >> (8 * k));
  return s;
#endif
}
__device__ __forceinline__ int q8(float v, float inv) {
  int q = (int)rintf(v * inv);
  return q > 127 ? 127 : (q < -127 ? -127 : q);
}
// 16-lane-row sum via DPP (VALU pipe, no LDS)
__device__ __forceinline__ int red16_i(int s) {
  s += __builtin_amdgcn_update_dpp(0, s, 0xB1, 0xF, 0xF, true);   // quad_perm [1,0,3,2]
  s += __builtin_amdgcn_update_dpp(0, s, 0x4E, 0xF, 0xF, true);   // quad_perm [2,3,0,1]
  s += __builtin_amdgcn_update_dpp(0, s, 0x141, 0xF, 0xF, true);  // row_half_mirror
  s += __builtin_amdgcn_update_dpp(0, s, 0x140, 0xF, 0xF, true);  // row_mirror
  return s;
}
#define DPP_D_LEVEL(v, ctrl)                                                        \
  {                                                                                 \
    uint64 u_ = (uint64)__double_as_longlong(v);                                    \
    int lo_ = __builtin_amdgcn_update_dpp(0, (int)(uint32)u_, (ctrl), 0xF, 0xF, true); \
    int hi_ = __builtin_amdgcn_update_dpp(0, (int)(uint32)(u_ >> 32), (ctrl), 0xF, 0xF, true); \
    (v) += __longlong_as_double((long long)(((uint64)(uint32)hi_ << 32) | (uint32)lo_)); \
  }
__device__ __forceinline__ double red16_d(double v) {
  DPP_D_LEVEL(v, 0xB1); DPP_D_LEVEL(v, 0x4E);
  DPP_D_LEVEL(v, 0x141); DPP_D_LEVEL(v, 0x140);
  return v;
}

// ---------- prep: [0,3584) Wall(896 rows) | [3584,11776) x -> xb bf16 pack ----------
__global__ __launch_bounds__(256) void prep_all(
    const float* __restrict__ Wfc, const float* __restrict__ Wbin,
    const float* __restrict__ x, ushort16* __restrict__ Wall,
    u32x4* __restrict__ xb) {
  const int blk = blockIdx.x;
  const int t = threadIdx.x;
  if (blk < 3584) {
    int idx = blk * 256 + t;                     // 896*1024
    int j = idx >> 10, n = idx & 1023;
    float v = 0.f;
    if (j < 12) v = Wfc[n * 12 + j];
    else if (j >= 64 && j < 832) v = Wbin[(size_t)(j - 64) * 1024 + n];
    Wall[idx] = f2bf(v);
  } else {
    int idx = (blk - 3584) * 256 + t;            // 2,097,152 threads x 8 floats
    const float4* s = (const float4*)x + (size_t)idx * 2;
    float4 a = s[0], b4 = s[1];
    u32x4 o;
    o.x = pk2(a.x, a.y);  o.y = pk2(a.z, a.w);
    o.z = pk2(b4.x, b4.y); o.w = pk2(b4.z, b4.w);
    xb[idx] = o;
  }
}

// ---------- legacy preps for fallback ----------
__global__ void prep_wall_f(const float* __restrict__ Wfc, const float* __restrict__ Wbin,
                            ushort16* __restrict__ Wall) {
  int idx = blockIdx.x * 256 + threadIdx.x;      // 896*1024
  int j = idx >> 10, n = idx & 1023;
  float v = 0.f;
  if (j < 12) v = Wfc[n * 12 + j];
  else if (j >= 64 && j < 832) v = Wbin[(size_t)(j - 64) * 1024 + n];
  Wall[idx] = f2bf(v);
}
__global__ void prep_wres(const float* __restrict__ Wres, ushort16* __restrict__ Wres_b) {
  int idx = blockIdx.x * 256 + threadIdx.x;
  int n = idx & 1023;
  int d = (idx >> 10) % 3;
  int ck = idx / 3072;
  Wres_b[idx] = f2bf(Wres[((size_t)ck * 1024 + n) * 3 + d]);
}

// ---------- legacy 128x128 gemm for fallback (256 thr, writes ybin) ----------
__global__ __launch_bounds__(256) void gemm_fb(
    const float* __restrict__ x, const float* __restrict__ bfc,
    const float* __restrict__ bbin, const ushort16* __restrict__ Wall,
    ushort16* __restrict__ ybin, float* __restrict__ out) {
  __shared__ __align__(16) char smem[32768];
  const int t = threadIdx.x;
  const int lane = t & 63, wid = t >> 6;
  const int wm = wid & 1, wn = wid >> 1;
  int orig = blockIdx.x;
  int bid = (orig & 7) * 112 + (orig >> 3);
  int nb = bid % 7, mb = bid / 7;
  const int b0 = mb * 128;
  f32x4 acc[4][4];
#pragma unroll
  for (int i = 0; i < 4; ++i)
#pragma unroll
    for (int j = 0; j < 4; ++j) acc[i][j] = (f32x4){0.f, 0.f, 0.f, 0.f};
  const int lr = lane & 15, lq = lane >> 4;
  const int fxor = (lr & 7) << 4;
  for (int kc = 0; kc < 1024; kc += 64) {
    __syncthreads();
    const int sxor = ((t >> 3) & 7) << 4;
#pragma unroll
    for (int i = 0; i < 4; ++i) {
      int s = t + i * 256;
      int row = s >> 3, c8 = (s & 7) * 8;
      int dst = row * 128 + ((c8 * 2) ^ sxor);
      const float4* src = (const float4*)(x + (size_t)(b0 + row) * 1024 + kc + c8);
      float4 v0 = src[0], v1 = src[1];
      u32x4 pv;
      pv.x = pk2(v0.x, v0.y); pv.y = pk2(v0.z, v0.w);
      pv.z = pk2(v1.x, v1.y); pv.w = pk2(v1.z, v1.w);
      *(u32x4*)(smem + dst) = pv;
    }
#pragma unroll
    for (int i = 0; i < 4; ++i) {
      int s = t + i * 256;
      int row = s >> 3, c8 = (s & 7) * 8;
      int dst = 16384 + row * 128 + ((c8 * 2) ^ sxor);
      u32x4 v = *(const u32x4*)(Wall + (size_t)(nb * 128 + row) * 1024 + kc + c8);
      *(u32x4*)(smem + dst) = v;
    }
    __syncthreads();
#pragma unroll
    for (int kk = 0; kk < 2; ++kk) {
      int cbx = (kk * 64 + lq * 16) ^ fxor;
      bf16x8 af[4], bfr[4];
#pragma unroll
      for (int i = 0; i < 4; ++i)
        af[i] = *(const bf16x8*)(smem + (wm * 64 + i * 16 + lr) * 128 + cbx);
#pragma unroll
      for (int j = 0; j < 4; ++j)
        bfr[j] = *(const bf16x8*)(smem + 16384 + (wn * 64 + j * 16 + lr) * 128 + cbx);
#pragma unroll
      for (int i = 0; i < 4; ++i)
#pragma unroll
        for (int j = 0; j < 4; ++j)
          acc[i][j] = __builtin_amdgcn_mfma_f32_16x16x32_bf16(af[i], bfr[j], acc[i][j], 0, 0, 0);
    }
  }
  const int g = 2 * nb + wn;
  if (g == 0) {
#pragma unroll
    for (int i = 0; i < 4; ++i)
#pragma unroll
      for (int r = 0; r < 4; ++r) {
        int gm = b0 + wm * 64 + i * 16 + lq * 4 + r;
        if (lr < 12) out[(size_t)gm * 12 + lr] = acc[i][0][r] + bfc[lr];
      }
    return;
  }
  if (g > 12) return;
  const int c = g - 1;
#pragma unroll
  for (int i = 0; i < 4; ++i)
#pragma unroll
    for (int j = 0; j < 4; ++j)
#pragma unroll
      for (int r = 0; r < 4; ++r) {
        int gm = b0 + wm * 64 + i * 16 + lq * 4 + r;
        int col = j * 16 + lr;
        ybin[((size_t)gm * 12 + c) * 64 + col] = f2bf(acc[i][j][r] + bbin[c * 64 + col]);
      }
}

// ---------- mega-kernel, 512 thr: [0,448) GEMM 256x128 | [448,544) Wres quant | [544,2592) xq ----------
__global__ __launch_bounds__(512) void gemm_mega(
    const float* __restrict__ x, const ushort16* __restrict__ xb,
    const float* __restrict__ bfc, const float* __restrict__ bbin,
    const ushort16* __restrict__ Wall, unsigned char* __restrict__ ind8,
    uint64* __restrict__ mask64, const float* __restrict__ Wres,
    uint32* __restrict__ wq, float* __restrict__ swk, uint32* __restrict__ xq,
    float* __restrict__ sxb, float* __restrict__ out) {
  extern __shared__ __align__(16) char smem[];   // 73728 B for gemm blocks
  const int t = threadIdx.x;
  const int lane = t & 63, wid = t >> 6;

  if (blockIdx.x >= 544) {
    // ---- xq + sxb prep, wave-per-row ----
    const int b = (blockIdx.x - 544) * 8 + wid;  // 2048 blocks x 8 waves
    const float4* xr = (const float4*)(x + (size_t)b * 1024 + lane * 16);
    float4 v0 = xr[0], v1 = xr[1], v2 = xr[2], v3 = xr[3];
    float xv[16] = {v0.x, v0.y, v0.z, v0.w, v1.x, v1.y, v1.z, v1.w,
                    v2.x, v2.y, v2.z, v2.w, v3.x, v3.y, v3.z, v3.w};
    float m = 0.f;
#pragma unroll
    for (int i = 0; i < 16; ++i) m = fmaxf(m, fabsf(xv[i]));
    for (int off = 32; off; off >>= 1) m = fmaxf(m, __shfl_xor(m, off));
    float mx = fmaxf(m, 1e-20f);
    float inv = 127.f / mx;
    if (lane == 0) sxb[b] = mx / 127.f;
    u32x4 qv;
#pragma unroll
    for (int q = 0; q < 4; ++q) {
      uint32 u = ((uint32)(unsigned char)(char)q8(xv[4 * q + 0], inv)) |
                 ((uint32)(unsigned char)(char)q8(xv[4 * q + 1], inv)) << 8 |
                 ((uint32)(unsigned char)(char)q8(xv[4 * q + 2], inv)) << 16 |
                 ((uint32)(unsigned char)(char)q8(xv[4 * q + 3], inv)) << 24;
      qv[q] = u;
    }
    ((u32x4*)(xq + (size_t)b * 256))[lane] = qv;
    return;
  }
  if (blockIdx.x >= 448) {
    // ---- Wres -> int8 quant, wave-per-ck ----
    const int ck = (blockIdx.x - 448) * 8 + wid; // 96 blocks x 8 waves = 768 experts
    const float4* base4 = (const float4*)(Wres + (size_t)ck * 3072);
    float m = 0.f;
#pragma unroll
    for (int it = 0; it < 4; ++it) {
      int tt = lane + 64 * it;
      float4 v0 = base4[3 * tt], v1 = base4[3 * tt + 1], v2 = base4[3 * tt + 2];
      m = fmaxf(m, fmaxf(fmaxf(fabsf(v0.x), fabsf(v0.y)), fmaxf(fabsf(v0.z), fabsf(v0.w))));
      m = fmaxf(m, fmaxf(fmaxf(fabsf(v1.x), fabsf(v1.y)), fmaxf(fabsf(v1.z), fabsf(v1.w))));
      m = fmaxf(m, fmaxf(fmaxf(fabsf(v2.x), fabsf(v2.y)), fmaxf(fabsf(v2.z), fabsf(v2.w))));
    }
    for (int off = 32; off; off >>= 1) m = fmaxf(m, __shfl_xor(m, off));
    float mx = fmaxf(m, 1e-20f);
    float inv = 127.f / mx;
    if (lane == 0) swk[ck] = mx / 127.f;
#pragma unroll
    for (int it = 0; it < 4; ++it) {
      int tt = lane + 64 * it;
      float4 v0 = base4[3 * tt], v1 = base4[3 * tt + 1], v2 = base4[3 * tt + 2];
      float vals[12] = {v0.x, v0.y, v0.z, v0.w, v1.x, v1.y, v1.z, v1.w, v2.x, v2.y, v2.z, v2.w};
#pragma unroll
      for (int d = 0; d < 3; ++d) {
        uint32 u = 0;
#pragma unroll
        for (int j = 0; j < 4; ++j)
          u |= ((uint32)(unsigned char)(char)q8(vals[j * 3 + d], inv)) << (8 * j);
        wq[((size_t)(ck * 3 + d) << 8) + tt] = u;
      }
    }
    return;
  }

  // ---- GEMM path: BM=256 BN=128 BK=32, 8 waves (4M x 2N) ----
  const int wm = wid & 3, wn = wid >> 2;

  int orig = blockIdx.x;
  int bid = (orig & 7) * 56 + (orig >> 3);       // XCD-bijective (448 = 8*56)
  int nb = bid % 7, mb = bid / 7;
  const int b0 = mb * 256;

  f32x4 acc[4][4];
#pragma unroll
  for (int i = 0; i < 4; ++i)
#pragma unroll
    for (int j = 0; j < 4; ++j) acc[i][j] = (f32x4){0.f, 0.f, 0.f, 0.f};

  const int lr = lane & 15, lq = lane >> 4;
  const int gs2 = (lane & 3) ^ ((lane >> 2) & 3);
  const int grw2 = lane >> 2;

#define GLDS(srcp, dstoff)                                                      \
  __builtin_amdgcn_global_load_lds(                                             \
      (const __attribute__((address_space(1))) uint32*)(srcp),                  \
      (__attribute__((address_space(3))) uint32*)(smem + (dstoff)), 16, 0, 0)

  const ushort16* srcp[3];
  int dsto[3];
#pragma unroll
  for (int k = 0; k < 3; ++k) {
    int c = wid * 3 + k;
    if (c < 16) {
      srcp[k] = xb + (size_t)(b0 + c * 16 + grw2) * 1024 + gs2 * 8;
      dsto[k] = c * 1024;
    } else {
      int cb = c - 16;
      srcp[k] = Wall + (size_t)(nb * 128 + cb * 16 + grw2) * 1024 + gs2 * 8;
      dsto[k] = 16384 + cb * 1024;
    }
  }

#define STAGE_HALF(h, buf)                                                      \
  {                                                                             \
    int bb_ = (buf) * 24576;                                                    \
    int kc_ = (h) * 32;                                                         \
    GLDS(srcp[0] + kc_, bb_ + dsto[0]);                                         \
    GLDS(srcp[1] + kc_, bb_ + dsto[1]);                                         \
    GLDS(srcp[2] + kc_, bb_ + dsto[2]);                                         \
  }

  STAGE_HALF(0, 0); STAGE_HALF(1, 1);
  const int cbx2 = (lq * 16) ^ ((lr & 3) << 4);
  const int arow_off = (wm * 64 + lr) * 64;
  const int brow_off = (wn * 64 + lr) * 64;
  int rb = 0;
#pragma unroll 1
  for (int h = 0; h < 32; ++h) {
    if (h < 31) asm volatile("s_waitcnt vmcnt(3)" ::: "memory");
    else        asm volatile("s_waitcnt vmcnt(0)" ::: "memory");
    __builtin_amdgcn_s_barrier();
    if (h < 30) {
      int sb = rb + 2; if (sb >= 3) sb -= 3;
      STAGE_HALF(h + 2, sb);
    }
    const char* base = smem + rb * 24576;
    bf16x8 af[4], bfr[4];
#pragma unroll
    for (int i = 0; i < 4; ++i)
      af[i] = *(const bf16x8*)(base + arow_off + i * 1024 + cbx2);
#pragma unroll
    for (int j = 0; j < 4; ++j)
      bfr[j] = *(const bf16x8*)(base + 16384 + brow_off + j * 1024 + cbx2);
#pragma unroll
    for (int i = 0; i < 4; ++i)
#pragma unroll
      for (int j = 0; j < 4; ++j)
        acc[i][j] = __builtin_amdgcn_mfma_f32_16x16x32_bf16(af[i], bfr[j], acc[i][j], 0, 0, 0);
    rb = (rb == 2) ? 0 : rb + 1;
  }
#undef STAGE_HALF
#undef GLDS

  // ---- epilogue ----
  const int g = 2 * nb + wn;                     // group id 0..13
  if (g == 0) {
#pragma unroll
    for (int i = 0; i < 4; ++i)
#pragma unroll
      for (int r = 0; r < 4; ++r) {
        int gm = b0 + wm * 64 + i * 16 + lq * 4 + r;
        if (lr < 12) out[(size_t)gm * 12 + lr] = acc[i][0][r] + bfc[lr];
      }
    return;
  }
  if (g > 12) return;
  const int c = g - 1;
  float bb[4];
#pragma unroll
  for (int j = 0; j < 4; ++j) bb[j] = bbin[c * 64 + j * 16 + lr];
#pragma unroll
  for (int i = 0; i < 4; ++i)
#pragma unroll
    for (int r = 0; r < 4; ++r) {
      float v0 = acc[i][0][r] + bb[0], v1 = acc[i][1][r] + bb[1];
      float v2 = acc[i][2][r] + bb[2], v3 = acc[i][3][r] + bb[3];
      float m1 = v0, m2 = -3.4e38f; int k1 = lr;
      if (v1 > m1) { m2 = m1; m1 = v1; k1 = 16 + lr; } else m2 = fmaxf(m2, v1);
      if (v2 > m1) { m2 = m1; m1 = v2; k1 = 32 + lr; } else m2 = fmaxf(m2, v2);
      if (v3 > m1) { m2 = m1; m1 = v3; k1 = 48 + lr; } else m2 = fmaxf(m2, v3);
#pragma unroll
      for (int off = 1; off < 16; off <<= 1) {
        float om1 = __shfl_xor(m1, off);
        int   ok1 = __shfl_xor(k1, off);
        float om2 = __shfl_xor(m2, off);
        bool take = (om1 > m1) || (om1 == m1 && ok1 < k1);
        float lose = take ? m1 : om1;
        m2 = fmaxf(fmaxf(m2, om2), lose);
        if (take) { m1 = om1; k1 = ok1; }
      }
      float thr = m1 - MARGIN;
      uint64 bl0 = __ballot(v0 >= thr);
      uint64 bl1 = __ballot(v1 >= thr);
      uint64 bl2 = __ballot(v2 >= thr);
      uint64 bl3 = __ballot(v3 >= thr);
      if (lr == 0) {
        int row = wm * 64 + i * 16 + lq * 4 + r;
        uint64 mk = ((bl0 >> (lq * 16)) & 0xffffull) |
                    (((bl1 >> (lq * 16)) & 0xffffull) << 16) |
                    (((bl2 >> (lq * 16)) & 0xffffull) << 32) |
                    (((bl3 >> (lq * 16)) & 0xffffull) << 48);
        int gp = (b0 + row) * 12 + c;
        ind8[gp] = (unsigned char)(k1 | ((m1 - m2 <= MARGIN) ? 128 : 0));
        mask64[gp] = mk;
      }
    }
}

// ---------- compact_k ----------
__global__ __launch_bounds__(256) void compact_k(const unsigned char* __restrict__ ind8,
                                                 uint32* __restrict__ cnt,
                                                 uint32* __restrict__ wl) {
  const int b = blockIdx.x * 256 + threadIdx.x;  // 64 blocks
  const int lane = threadIdx.x & 63;
  const uint32* p = (const uint32*)(ind8 + b * 12);
  uint32 d0 = p[0], d1 = p[1], d2 = p[2];
  uint32 fmask = 0;
#pragma unroll
  for (int j = 0; j < 4; ++j) {
    if ((d0 >> (8 * j)) & 128u) fmask |= 1u << j;
    if ((d1 >> (8 * j)) & 128u) fmask |= 1u << (4 + j);
    if ((d2 >> (8 * j)) & 128u) fmask |= 1u << (8 + j);
  }
  uint32 n_i = (uint32)__popc(fmask);
  uint32 pre = n_i;
  for (int off = 1; off < 64; off <<= 1) {
    uint32 v = __shfl_up(pre, off);
    if (lane >= off) pre += v;
  }
  uint32 total = __shfl(pre, 63);
  uint32 base = 0;
  if (lane == 63 && total) base = atomicAdd(cnt, total);
  base = __shfl(base, 63);
  uint32 off = base + pre - n_i;
  while (fmask) {
    int c = __ffs(fmask) - 1;
    fmask &= fmask - 1;
    wl[off++] = (uint32)(b * 12 + c);
  }
}

// ---------- tail_k (grid 12288): bid%3<2 -> rescue (8192 blks); ==2 -> gather 1-wave-per-b ----------
__global__ __launch_bounds__(256) void tail_k(
    const float* __restrict__ x, const float* __restrict__ Wbin,
    const float* __restrict__ bbin, const float* __restrict__ bres,
    const float* __restrict__ centers, const unsigned char* __restrict__ ind8,
    const uint64* __restrict__ mask64, const uint32* __restrict__ wq,
    const float* __restrict__ swk, const uint32* __restrict__ xq,
    const float* __restrict__ sxb, const uint32* __restrict__ cnt,
    const uint32* __restrict__ wl, float* __restrict__ out) {
  const int lane = threadIdx.x & 63;
  const int w = threadIdx.x >> 6;
  const int rm = (int)(blockIdx.x % 3u);
  const int rq = (int)(blockIdx.x / 3u);

  if (rm < 2) {
    // ---- per-pair rescue; 8192 blocks -> 32768 wave slots, grid-stride ----
    const uint32 nresc = *cnt;
#pragma unroll 1
    for (uint32 slot = (uint32)(rq * 2 + rm) * 4 + w; slot < nresc; slot += 32768) {
      const uint32 pp = wl[slot];
      const int b = (int)(pp / 12u), c = (int)(pp % 12u);

      float xv[16];
      const float4* xr = (const float4*)(x + (size_t)b * 1024 + lane * 16);
#pragma unroll
      for (int q = 0; q < 4; ++q) {
        float4 vv = xr[q];
        xv[4 * q] = vv.x; xv[4 * q + 1] = vv.y; xv[4 * q + 2] = vv.z; xv[4 * q + 3] = vv.w;
      }
      const float sx = sxb[b];
      const float inv = (sx > 0.f) ? 1.f / sx : 0.f;
      uint32 xi[4];
#pragma unroll
      for (int q = 0; q < 4; ++q)
        xi[q] = ((uint32)(unsigned char)(char)q8(xv[4 * q + 0], inv)) |
                ((uint32)(unsigned char)(char)q8(xv[4 * q + 1], inv)) << 8 |
                ((uint32)(unsigned char)(char)q8(xv[4 * q + 2], inv)) << 16 |
                ((uint32)(unsigned char)(char)q8(xv[4 * q + 3], inv)) << 24;

      uint64 mask = mask64[pp];
      double best = -1.0e300;
      int bk = 0;
#pragma unroll 1
      while (mask) {
        int kk[4];
        int nc = 0;
        while (mask && nc < 4) { kk[nc++] = __ffsll(mask) - 1; mask &= mask - 1; }
#pragma unroll
        for (int j = 1; j < 4; ++j) if (j >= nc) kk[j] = kk[0];
        double s[4] = {0.0, 0.0, 0.0, 0.0};
#pragma unroll
        for (int ci = 0; ci < 4; ++ci) {
          const float4* wr4 = (const float4*)(Wbin + ((size_t)c * 64 + kk[ci]) * 1024 + lane * 16);
#pragma unroll
          for (int q = 0; q < 4; ++q) {
            float4 wvv = wr4[q];
            s[ci] += (double)xv[4 * q] * (double)wvv.x + (double)xv[4 * q + 1] * (double)wvv.y +
                     (double)xv[4 * q + 2] * (double)wvv.z + (double)xv[4 * q + 3] * (double)wvv.w;
          }
        }
#pragma unroll
        for (int ci = 0; ci < 4; ++ci) s[ci] = red16_d(s[ci]);   // DPP 16-lane sums
        for (int off = 16; off < 64; off <<= 1) {
#pragma unroll
          for (int ci = 0; ci < 4; ++ci) s[ci] += __shfl_xor(s[ci], off);
        }
#pragma unroll
        for (int ci = 0; ci < 4; ++ci) {
          double sv = s[ci] + (double)bbin[c * 64 + kk[ci]];
          if (ci < nc && sv > best) { best = sv; bk = kk[ci]; }  // ascending k, strict >
        }
      }
      const int ck = c * 64 + bk;
      const uint32* wr = wq + (size_t)ck * 768;
      int acc[3];
#pragma unroll
      for (int d = 0; d < 3; ++d) {
        u32x4 wvq = *(const u32x4*)(wr + d * 256 + lane * 4);
        int ss = dot4(xi[0], wvq.x, 0);
        ss = dot4(xi[1], wvq.y, ss);
        ss = dot4(xi[2], wvq.z, ss);
        acc[d] = dot4(xi[3], wvq.w, ss);
      }
#pragma unroll
      for (int d = 0; d < 3; ++d) acc[d] = red16_i(acc[d]);
      for (int off = 16; off < 64; off <<= 1) {
        acc[0] += __shfl_xor(acc[0], off);
        acc[1] += __shfl_xor(acc[1], off);
        acc[2] += __shfl_xor(acc[2], off);
      }
      if (lane == 0) {
        const size_t obase = (size_t)B_SZ * 12 + (size_t)b * 36;
        float sc = sx * swk[ck];
        out[obase + 0 * 12 + c] = centers[bk * 3 + 0] + bres[ck * 3 + 0] + sc * (float)acc[0];
        out[obase + 1 * 12 + c] = centers[bk * 3 + 1] + bres[ck * 3 + 1] + sc * (float)acc[1];
        out[obase + 2 * 12 + c] = centers[bk * 3 + 2] + bres[ck * 3 + 2] + sc * (float)acc[2];
      }
    }
    return;
  }

  // ---- gather: 1 wave per b (4 b's per block); 12 classes in 4 groups of 3 ----
  const int b = rq * 4 + w;                      // 4096 gather blocks -> 16384 b's

  const u32x4 xi = *(const u32x4*)(xq + (size_t)b * 256 + lane * 4);
  const float sx = sxb[b];
  const size_t obase = (size_t)B_SZ * 12 + (size_t)b * 36;

  const uint32* pv = (const uint32*)(ind8 + b * 12);
  uint32 ivd[3] = {pv[0], pv[1], pv[2]};

#pragma unroll
  for (int cg = 0; cg < 4; ++cg) {
    int iv[3], ind[3], ck[3];
    u32x4 wv[3][3];
#pragma unroll
    for (int cc = 0; cc < 3; ++cc) {
      int c = cg * 3 + cc;
      iv[cc] = (int)((ivd[c >> 2] >> ((c & 3) * 8)) & 255u);
      ind[cc] = iv[cc] & 63;
      ck[cc] = c * 64 + ind[cc];
      const uint32* wr = wq + (size_t)ck[cc] * 768;
#pragma unroll
      for (int d = 0; d < 3; ++d)
        wv[cc][d] = *(const u32x4*)(wr + d * 256 + lane * 4);
    }
    int acc[3][3];
#pragma unroll
    for (int cc = 0; cc < 3; ++cc)
#pragma unroll
      for (int d = 0; d < 3; ++d) {
        int s = dot4(xi.x, wv[cc][d].x, 0);
        s = dot4(xi.y, wv[cc][d].y, s);
        s = dot4(xi.z, wv[cc][d].z, s);
        acc[cc][d] = dot4(xi.w, wv[cc][d].w, s);
      }
#pragma unroll
    for (int cc = 0; cc < 3; ++cc)
#pragma unroll
      for (int d = 0; d < 3; ++d)
        acc[cc][d] = red16_i(acc[cc][d]);        // DPP 16-lane sums (VALU pipe)
    for (int off = 16; off < 64; off <<= 1) {
#pragma unroll
      for (int cc = 0; cc < 3; ++cc)
#pragma unroll
        for (int d = 0; d < 3; ++d)
          acc[cc][d] += __shfl_xor(acc[cc][d], off);
    }
    if (lane == 0) {
#pragma unroll
      for (int cc = 0; cc < 3; ++cc) {
        if (iv[cc] & 128) continue;              // flagged written by rescue path
        int c = cg * 3 + cc;
        float sc = sx * swk[ck[cc]];
        out[obase + 0 * 12 + c] = centers[ind[cc] * 3 + 0] + bres[ck[cc] * 3 + 0] + sc * (float)acc[cc][0];
        out[obase + 1 * 12 + c] = centers[ind[cc] * 3 + 1] + bres[ck[cc] * 3 + 1] + sc * (float)acc[cc][1];
        out[obase + 2 * 12 + c] = centers[ind[cc] * 3 + 2] + bres[ck[cc] * 3 + 2] + sc * (float)acc[cc][2];
      }
    }
  }
}

// ---------- fallback select (bf16 Wres_b, f32 x, reads ybin) ----------
__global__ __launch_bounds__(256) void select2(
    const float* __restrict__ x, const float* __restrict__ Wbin,
    const float* __restrict__ bbin, const float* __restrict__ bres,
    const float* __restrict__ centers, const ushort16* __restrict__ Wres_b,
    const ushort16* __restrict__ ybin, float* __restrict__ out) {
  const int lane = threadIdx.x & 63;
  const int w = threadIdx.x >> 6;
  const int b = blockIdx.x;
  float xv[16];
  {
    const float4* xr = (const float4*)(x + (size_t)b * 1024 + lane * 16);
#pragma unroll
    for (int q = 0; q < 4; ++q) {
      float4 v = xr[q];
      xv[4 * q] = v.x; xv[4 * q + 1] = v.y; xv[4 * q + 2] = v.z; xv[4 * q + 3] = v.w;
    }
  }
  const size_t obase = (size_t)B_SZ * 12 + (size_t)b * 36;
#pragma unroll 1
  for (int cc = 0; cc < 3; ++cc) {
    const int c = w * 3 + cc;
    float v = bf2f(ybin[((size_t)b * 12 + c) * 64 + lane]);
    float m1 = v, m2 = -3.4e38f;
    int k1 = lane;
    for (int off = 32; off; off >>= 1) {
      float om1 = __shfl_xor(m1, off);
      int   ok1 = __shfl_xor(k1, off);
      float om2 = __shfl_xor(m2, off);
      bool take = (om1 > m1) || (om1 == m1 && ok1 < k1);
      float lose = take ? m1 : om1;
      m2 = fmaxf(fmaxf(m2, om2), lose);
      if (take) { m1 = om1; k1 = ok1; }
    }
    int ind = k1;
    if (m1 - m2 <= MARGIN) {
      unsigned long long mask = __ballot(v >= m1 - MARGIN);
      double best = -1.0e300;
      int bk = 0;
      while (mask) {
        int k = __ffsll(mask) - 1;
        mask &= (mask - 1);
        const float4* wr4 = (const float4*)(Wbin + ((size_t)c * 64 + k) * 1024 + lane * 16);
        double s = 0.0;
#pragma unroll
        for (int q = 0; q < 4; ++q) {
          float4 wv = wr4[q];
          s += (double)xv[4 * q] * (double)wv.x + (double)xv[4 * q + 1] * (double)wv.y +
               (double)xv[4 * q + 2] * (double)wv.z + (double)xv[4 * q + 3] * (double)wv.w;
        }
        for (int off = 32; off; off >>= 1) s += __shfl_xor(s, off);
        s += (double)bbin[c * 64 + k];
        if (s > best) { best = s; bk = k; }
      }
      ind = bk;
    }
    const ushort16* wr = Wres_b + ((size_t)(c * 64 + ind) * 3) * 1024;
    float a[3] = {0.f, 0.f, 0.f};
#pragma unroll
    for (int d = 0; d < 3; ++d) {
      const u32x4* pp = (const u32x4*)(wr + d * 1024 + lane * 16);
      u32x4 w0 = pp[0], w1 = pp[1];
      uint32 uw[8] = {w0.x, w0.y, w0.z, w0.w, w1.x, w1.y, w1.z, w1.w};
#pragma unroll
      for (int q = 0; q < 8; ++q) {
        a[d] = fmaf(xv[2 * q],     bflo(uw[q]), a[d]);
        a[d] = fmaf(xv[2 * q + 1], bfhi(uw[q]), a[d]);
      }
    }
    for (int off = 32; off; off >>= 1) {
      a[0] += __shfl_xor(a[0], off);
      a[1] += __shfl_xor(a[1], off);
      a[2] += __shfl_xor(a[2], off);
    }
    if (lane == 0) {
      int ck = c * 64 + ind;
      out[obase + 0 * 12 + c] = centers[ind * 3 + 0] + bres[ck * 3 + 0] + a[0];
      out[obase + 1 * 12 + c] = centers[ind * 3 + 1] + bres[ck * 3 + 1] + a[1];
      out[obase + 2 * 12 + c] = centers[ind * 3 + 2] + bres[ck * 3 + 2] + a[2];
    }
  }
}

extern "C" void kernel_launch(void* const* d_in, const int* in_sizes, int n_in,
                              void* d_out, int out_size, void* d_ws, size_t ws_size,
                              hipStream_t stream) {
  const float* x       = (const float*)d_in[0];
  const float* Wfc     = (const float*)d_in[1];
  const float* bfc     = (const float*)d_in[2];
  const float* Wbin    = (const float*)d_in[3];
  const float* bbin    = (const float*)d_in[4];
  const float* Wres    = (const float*)d_in[5];
  const float* bres    = (const float*)d_in[6];
  const float* centers = (const float*)d_in[7];
  float* out = (float*)d_out;

  char* ws = (char*)d_ws;
  ushort16* Wall = (ushort16*)ws;                              // 896*1024*2 = 1,835,008 B
  if (ws_size >= 57151488ull) {
    uint32*        wq     = (uint32*)(ws + 1835008);           // 2,359,296 B
    float*         swk    = (float*)(ws + 4194304);            // 3,072 B
    unsigned char* ind8   = (unsigned char*)(ws + 4197376);    // 196,608 B
    uint64*        mask64 = (uint64*)(ws + 4393984);           // 1,572,864 B
    ushort16*      xb     = (ushort16*)(ws + 5966848);         // 33,554,432 B
    uint32*        xq     = (uint32*)(ws + 39521280);          // 16,777,216 B
    float*         sxb    = (float*)(ws + 56298496);           // 65,536 B
    uint32*        cnt    = (uint32*)(ws + 56364032);          // 256 B (pad)
    uint32*        wl     = (uint32*)(ws + 56364288);          // 786,432 B -> end 57,150,720

    (void)hipFuncSetAttribute((const void*)gemm_mega,
                              hipFuncAttributeMaxDynamicSharedMemorySize, 73728);
    hipMemsetAsync(cnt, 0, 4, stream);
    prep_all<<<11776, 256, 0, stream>>>(Wfc, Wbin, x, Wall, (u32x4*)xb);
    gemm_mega<<<2592, 512, 73728, stream>>>(x, xb, bfc, bbin, Wall, ind8, mask64,
                                            Wres, wq, swk, xq, sxb, out);
    compact_k<<<64, 256, 0, stream>>>(ind8, cnt, wl);
    tail_k<<<12288, 256, 0, stream>>>(x, Wbin, bbin, bres, centers, ind8, mask64,
                                      wq, swk, xq, sxb, cnt, wl, out);
  } else {
    // fallback: ybin + bf16 select path
    ushort16* Wres_b = (ushort16*)(ws + 1835008);              // 4,718,592 B
    ushort16* ybin   = (ushort16*)(ws + 6553600);              // 25,165,824 B
    prep_wall_f<<<3584, 256, 0, stream>>>(Wfc, Wbin, Wall);
    prep_wres<<<9216, 256, 0, stream>>>(Wres, Wres_b);
    gemm_fb<<<896, 256, 0, stream>>>(x, bfc, bbin, Wall, ybin, out);
    select2<<<B_SZ, 256, 0, stream>>>(x, Wbin, bbin, bres, centers, Wres_b, ybin, out);
  }
}